// Round 1
// baseline (643.876 us; speedup 1.0000x reference)
//
#include <hip/hip_runtime.h>
#include <hip/hip_bf16.h>

#define N_NODES 50000
#define NREL 16
#define HID 64
#define NCLS 16
#define CHUNK 1024

// ---------------------------------------------------------------------------
// K2: per-(relation,dst) edge counts (shared by both layers)
// ---------------------------------------------------------------------------
__global__ __launch_bounds__(256) void count_k(const int* __restrict__ dstp,
                                               const int* __restrict__ et,
                                               float* __restrict__ cnt, int E) {
    int i = blockIdx.x * 256 + threadIdx.x;
    if (i < E) {
        unsafeAtomicAdd(&cnt[(size_t)et[i] * N_NODES + dstp[i]], 1.0f);
    }
}

// ---------------------------------------------------------------------------
// K3: X1 = x @ root1 + b1   (one wave per node, lane = out dim)
// ---------------------------------------------------------------------------
__global__ __launch_bounds__(256) void init1(const float* __restrict__ x,
                                             const float* __restrict__ root1,
                                             const float* __restrict__ b1,
                                             float* __restrict__ X1) {
    int gid = blockIdx.x * 256 + threadIdx.x;
    int node = gid >> 6;
    int d = gid & 63;
    if (node >= N_NODES) return;
    const float* xr = x + (size_t)node * HID;
    float h0 = b1[d], h1 = 0.f, h2 = 0.f, h3 = 0.f;
#pragma unroll
    for (int k = 0; k < HID; k += 4) {
        h0 = fmaf(xr[k + 0], root1[(k + 0) * HID + d], h0);
        h1 = fmaf(xr[k + 1], root1[(k + 1) * HID + d], h1);
        h2 = fmaf(xr[k + 2], root1[(k + 2) * HID + d], h2);
        h3 = fmaf(xr[k + 3], root1[(k + 3) * HID + d], h3);
    }
    X1[(size_t)node * HID + d] = (h0 + h1) + (h2 + h3);
}

// ---------------------------------------------------------------------------
// K4: layer-1 edge scatter. One wave owns (relation, 1024-edge chunk).
// Lane d holds column d of W1[rel] in 64 VGPRs. Ballot-scan for type
// matches; per match: wave-uniform x-row (scalar loads), 64 FMAs/lane,
// scaled atomic scatter to X1[dst].
// ---------------------------------------------------------------------------
__global__ __launch_bounds__(256) void edge_l1(const int* __restrict__ srcp,
                                               const int* __restrict__ dstp,
                                               const int* __restrict__ et,
                                               const float* __restrict__ x,
                                               const float* __restrict__ W1,
                                               const float* __restrict__ cnt,
                                               float* __restrict__ X1,
                                               int E, int chunksPerRel) {
    int gwave = (blockIdx.x * 256 + threadIdx.x) >> 6;
    int lane = threadIdx.x & 63;
    int rel = gwave / chunksPerRel;
    int chunk = gwave - rel * chunksPerRel;
    if (rel >= NREL) return;

    // Per-lane column of W1[rel]: Wc[k] = W1[rel][k][lane]
    float Wc[HID];
#pragma unroll
    for (int k = 0; k < HID; ++k)
        Wc[k] = W1[(size_t)rel * HID * HID + (size_t)k * HID + lane];

    int base = chunk * CHUNK;
    int end = base + CHUNK;
    if (end > E) end = E;

    for (int b = base; b < end; b += 64) {
        int e = b + lane;
        int t = (e < end) ? et[e] : -1;
        unsigned long long mask = __ballot(t == rel);
        while (mask) {
            int bit = __ffsll((unsigned long long)mask) - 1;
            mask &= (mask - 1);
            int ee = b + bit;  // wave-uniform
            int s = __builtin_amdgcn_readfirstlane(srcp[ee]);
            int dd = __builtin_amdgcn_readfirstlane(dstp[ee]);
            float inv = 1.0f / cnt[(size_t)rel * N_NODES + dd];
            const float* xr = x + (size_t)s * HID;  // uniform -> scalar loads
            float h0 = 0.f, h1 = 0.f, h2 = 0.f, h3 = 0.f;
#pragma unroll
            for (int k = 0; k < HID; k += 4) {
                h0 = fmaf(xr[k + 0], Wc[k + 0], h0);
                h1 = fmaf(xr[k + 1], Wc[k + 1], h1);
                h2 = fmaf(xr[k + 2], Wc[k + 2], h2);
                h3 = fmaf(xr[k + 3], Wc[k + 3], h3);
            }
            float h = (h0 + h1) + (h2 + h3);
            unsafeAtomicAdd(&X1[(size_t)dd * HID + lane], h * inv);
        }
    }
}

// ---------------------------------------------------------------------------
// K5: in-place ReLU on X1
// ---------------------------------------------------------------------------
__global__ __launch_bounds__(256) void relu_k(float* __restrict__ X1, int n) {
    int i = blockIdx.x * 256 + threadIdx.x;
    if (i < n) X1[i] = fmaxf(X1[i], 0.0f);
}

// ---------------------------------------------------------------------------
// K6: out = X1 @ root2 + b2   (thread per (node, class))
// ---------------------------------------------------------------------------
__global__ __launch_bounds__(256) void init2(const float* __restrict__ X1,
                                             const float* __restrict__ root2,
                                             const float* __restrict__ b2,
                                             float* __restrict__ out) {
    int gid = blockIdx.x * 256 + threadIdx.x;
    int node = gid >> 4;
    int d = gid & 15;
    if (node >= N_NODES) return;
    const float* xr = X1 + (size_t)node * HID;
    float h0 = b2[d], h1 = 0.f, h2 = 0.f, h3 = 0.f;
#pragma unroll
    for (int k = 0; k < HID; k += 4) {
        h0 = fmaf(xr[k + 0], root2[(k + 0) * NCLS + d], h0);
        h1 = fmaf(xr[k + 1], root2[(k + 1) * NCLS + d], h1);
        h2 = fmaf(xr[k + 2], root2[(k + 2) * NCLS + d], h2);
        h3 = fmaf(xr[k + 3], root2[(k + 3) * NCLS + d], h3);
    }
    out[(size_t)node * NCLS + d] = (h0 + h1) + (h2 + h3);
}

// ---------------------------------------------------------------------------
// K7: layer-2 edge scatter. Wave owns (relation, chunk). Lane = (q, d):
// q = lane>>4 covers K-quarter, d = lane&15 the class. 16 FMAs/lane,
// shfl_xor reduction over quarters, 16-lane atomic scatter.
// ---------------------------------------------------------------------------
__global__ __launch_bounds__(256) void edge_l2(const int* __restrict__ srcp,
                                               const int* __restrict__ dstp,
                                               const int* __restrict__ et,
                                               const float* __restrict__ X1,
                                               const float* __restrict__ W2,
                                               const float* __restrict__ cnt,
                                               float* __restrict__ out,
                                               int E, int chunksPerRel) {
    int gwave = (blockIdx.x * 256 + threadIdx.x) >> 6;
    int lane = threadIdx.x & 63;
    int d = lane & 15;
    int q = lane >> 4;
    int rel = gwave / chunksPerRel;
    int chunk = gwave - rel * chunksPerRel;
    if (rel >= NREL) return;

    // Per-lane slice of W2[rel]: Wc[j] = W2[rel][q*16+j][d]
    float Wc[16];
#pragma unroll
    for (int j = 0; j < 16; ++j)
        Wc[j] = W2[(size_t)rel * HID * NCLS + (size_t)(q * 16 + j) * NCLS + d];

    int base = chunk * CHUNK;
    int end = base + CHUNK;
    if (end > E) end = E;

    for (int b = base; b < end; b += 64) {
        int e = b + lane;
        int t = (e < end) ? et[e] : -1;
        unsigned long long mask = __ballot(t == rel);
        while (mask) {
            int bit = __ffsll((unsigned long long)mask) - 1;
            mask &= (mask - 1);
            int ee = b + bit;  // wave-uniform
            int s = __builtin_amdgcn_readfirstlane(srcp[ee]);
            int dd = __builtin_amdgcn_readfirstlane(dstp[ee]);
            float inv = 1.0f / cnt[(size_t)rel * N_NODES + dd];
            const float4* xr4 = (const float4*)(X1 + (size_t)s * HID);
            float h = 0.f;
#pragma unroll
            for (int j4 = 0; j4 < 4; ++j4) {
                float4 xv = xr4[q * 4 + j4];
                h = fmaf(xv.x, Wc[j4 * 4 + 0], h);
                h = fmaf(xv.y, Wc[j4 * 4 + 1], h);
                h = fmaf(xv.z, Wc[j4 * 4 + 2], h);
                h = fmaf(xv.w, Wc[j4 * 4 + 3], h);
            }
            h += __shfl_xor(h, 16, 64);
            h += __shfl_xor(h, 32, 64);
            if (q == 0) {
                unsafeAtomicAdd(&out[(size_t)dd * NCLS + d], h * inv);
            }
        }
    }
}

extern "C" void kernel_launch(void* const* d_in, const int* in_sizes, int n_in,
                              void* d_out, int out_size, void* d_ws, size_t ws_size,
                              hipStream_t stream) {
    const int* ei    = (const int*)d_in[0];   // [2, E] : src row then dst row
    const int* et    = (const int*)d_in[1];   // [E]
    const float* x   = (const float*)d_in[2]; // [N, 64]
    const float* W1  = (const float*)d_in[3]; // [16, 64, 64]
    const float* r1  = (const float*)d_in[4]; // [64, 64]
    const float* b1  = (const float*)d_in[5]; // [64]
    const float* W2  = (const float*)d_in[6]; // [16, 64, 16]
    const float* r2  = (const float*)d_in[7]; // [64, 16]
    const float* b2  = (const float*)d_in[8]; // [16]
    float* out = (float*)d_out;               // [N, 16]

    int E = in_sizes[0] / 2;
    const int* srcp = ei;
    const int* dstp = ei + E;

    // Workspace layout: cnt [16*50000] f32 (3.2 MB), X1 [50000*64] f32 (12.8 MB)
    float* cnt = (float*)d_ws;
    float* X1 = cnt + (size_t)NREL * N_NODES;

    hipMemsetAsync(cnt, 0, (size_t)NREL * N_NODES * sizeof(float), stream);

    count_k<<<(E + 255) / 256, 256, 0, stream>>>(dstp, et, cnt, E);

    init1<<<(N_NODES * HID + 255) / 256, 256, 0, stream>>>(x, r1, b1, X1);

    int chunksPerRel = (E + CHUNK - 1) / CHUNK;
    int waves = NREL * chunksPerRel;
    int blocks = (waves * 64 + 255) / 256;

    edge_l1<<<blocks, 256, 0, stream>>>(srcp, dstp, et, x, W1, cnt, X1, E, chunksPerRel);

    relu_k<<<(N_NODES * HID + 255) / 256, 256, 0, stream>>>(X1, N_NODES * HID);

    init2<<<(N_NODES * NCLS + 255) / 256, 256, 0, stream>>>(X1, r2, b2, out);

    edge_l2<<<blocks, 256, 0, stream>>>(srcp, dstp, et, X1, W2, cnt, out, E, chunksPerRel);
}